// Round 1
// baseline (235.498 us; speedup 1.0000x reference)
//
#include <hip/hip_runtime.h>
#include <math.h>

#define VOCAB 32000
#define EMBED 200
#define HID   10
#define GATES 40
#define BSZ   256
#define SEQ   512

__device__ __forceinline__ float rcp_fast(float x) { return __builtin_amdgcn_rcpf(x); }

// sigmoid(x) = 1/(1+exp(-x)); tanh(x) = 2*sigmoid(2x)-1
__device__ __forceinline__ float sigmoid_fast(float x) {
    return rcp_fast(1.0f + __expf(-x));
}

// ---------------------------------------------------------------------------
// Kernel A: proj[v][g] = dot(embed_W[v,:], W_ih[g,:]) + b_ih[g] + b_hh[g]
// One wave (64 threads) per vocab row per grid-stride iteration; lanes 0..39
// each compute one gate. embed row loads are wave-uniform (scalarizable);
// W_ih rows are L1-resident after first touch.
// ---------------------------------------------------------------------------
__global__ __launch_bounds__(64) void proj_kernel(
    const float* __restrict__ embed, const float* __restrict__ Wih,
    const float* __restrict__ bih,   const float* __restrict__ bhh,
    float* __restrict__ proj)
{
    const int lane = threadIdx.x;
    const int gl   = lane < GATES ? lane : GATES - 1;   // clamp idle lanes
    const float bias = bih[gl] + bhh[gl];
    const float4* wr = (const float4*)(Wih + gl * EMBED);

    for (int v = blockIdx.x; v < VOCAB; v += gridDim.x) {
        const float4* er = (const float4*)(embed + v * EMBED);
        float acc0 = 0.f, acc1 = 0.f;
        #pragma unroll 5
        for (int k = 0; k < EMBED / 4; k += 2) {
            float4 e0 = er[k];     float4 w0 = wr[k];
            float4 e1 = er[k + 1]; float4 w1 = wr[k + 1];
            acc0 = fmaf(e0.x, w0.x, acc0); acc0 = fmaf(e0.y, w0.y, acc0);
            acc0 = fmaf(e0.z, w0.z, acc0); acc0 = fmaf(e0.w, w0.w, acc0);
            acc1 = fmaf(e1.x, w1.x, acc1); acc1 = fmaf(e1.y, w1.y, acc1);
            acc1 = fmaf(e1.z, w1.z, acc1); acc1 = fmaf(e1.w, w1.w, acc1);
        }
        if (lane < GATES) proj[v * GATES + lane] = acc0 + acc1 + bias;
    }
}

// ---------------------------------------------------------------------------
// Kernel B: the recurrence. One wave per batch element (256 blocks x 64 thr =
// 1 wave per CU). Lane g in [0,40) owns gate g (i:0-9, f:10-19, g:20-29,
// o:30-39). h replicated in 10 regs/lane; c owned by lanes 0..9.
// gx for step s+1 and token for step s+2 are prefetched each iteration.
// ---------------------------------------------------------------------------
__global__ __launch_bounds__(64) void lstm_rec(
    const int*   __restrict__ tok,  const float* __restrict__ proj,
    const float* __restrict__ h0,   const float* __restrict__ c0,
    const float* __restrict__ Whh,
    const float* __restrict__ W1,   const float* __restrict__ b1,
    const float* __restrict__ lng,  const float* __restrict__ lnb,
    const float* __restrict__ W2,   const float* __restrict__ b2,
    float* __restrict__ out)
{
    __shared__ int tok_s[SEQ];
    const int b    = blockIdx.x;
    const int lane = threadIdx.x;
    const int gl   = lane < GATES ? lane : GATES - 1;

    #pragma unroll
    for (int k = 0; k < SEQ / 64; ++k)
        tok_s[k * 64 + lane] = tok[b * SEQ + k * 64 + lane];
    __syncthreads();

    // W_hh row for this gate
    float w[HID];
    #pragma unroll
    for (int j = 0; j < HID; ++j) w[j] = Whh[gl * HID + j];

    // replicated h, owned c
    float h_rep[HID];
    #pragma unroll
    for (int j = 0; j < HID; ++j) h_rep[j] = h0[b * HID + j];
    float c_own = (lane < HID) ? c0[b * HID + lane] : 0.f;

    // tanh-vs-sigmoid multiplier: gate lanes 20..29 compute tanh
    const float am  = (lane >= 20 && lane < 30) ? 2.f : 1.f;
    const int   j0  = lane % HID;
    const int   li  = j0, lf = j0 + 10, lg = j0 + 20, lo = j0 + 30;

    // prefetch pipeline: gx_cur ready for s, ts_nxt = token[s+1]
    int   ts_cur = tok_s[0];
    float gx_cur = proj[ts_cur * GATES + gl];
    int   ts_nxt = tok_s[1];

    for (int s = 0; s < SEQ; ++s) {
        // issue prefetches for s+1 (gx) and s+2 (token) up front
        float gx_next = proj[ts_nxt * GATES + gl];
        int   ts2     = tok_s[(s + 2 < SEQ) ? s + 2 : SEQ - 1];

        // gates = gx + h . Whh_row   (two independent FMA chains)
        float a0 = gx_cur, a1 = 0.f;
        a0 = fmaf(h_rep[0], w[0], a0); a1 = fmaf(h_rep[1], w[1], a1);
        a0 = fmaf(h_rep[2], w[2], a0); a1 = fmaf(h_rep[3], w[3], a1);
        a0 = fmaf(h_rep[4], w[4], a0); a1 = fmaf(h_rep[5], w[5], a1);
        a0 = fmaf(h_rep[6], w[6], a0); a1 = fmaf(h_rep[7], w[7], a1);
        a0 = fmaf(h_rep[8], w[8], a0); a1 = fmaf(h_rep[9], w[9], a1);
        float acc = a0 + a1;

        // branchless sigmoid/tanh: val = am*sigmoid(am*acc) - (am-1)
        float sg  = sigmoid_fast(am * acc);
        float val = fmaf(am, sg, 1.f - am);

        // gather i,f,g,o for hidden unit j0
        float iv = __shfl(val, li, 64);
        float fv = __shfl(val, lf, 64);
        float gv = __shfl(val, lg, 64);
        float ov = __shfl(val, lo, 64);

        c_own = fmaf(fv, c_own, iv * gv);                 // c = f*c + i*g
        float th    = fmaf(2.f, sigmoid_fast(2.f * c_own), -1.f); // tanh(c)
        float h_own = ov * th;

        // re-broadcast h to all lanes
        #pragma unroll
        for (int j = 0; j < HID; ++j) h_rep[j] = __shfl(h_own, j, 64);

        gx_cur = gx_next;
        ts_nxt = ts2;
    }

    // head: z = hn@W1^T + b1 ; LayerNorm(5) ; sigmoid(z@W2^T + b2)
    if (lane == 0) {
        float z[5];
        float mu = 0.f;
        #pragma unroll
        for (int m = 0; m < 5; ++m) {
            float a = b1[m];
            #pragma unroll
            for (int j = 0; j < HID; ++j) a = fmaf(h_rep[j], W1[m * HID + j], a);
            z[m] = a; mu += a;
        }
        mu *= 0.2f;
        float var = 0.f;
        #pragma unroll
        for (int m = 0; m < 5; ++m) { float d = z[m] - mu; var = fmaf(d, d, var); }
        var *= 0.2f;
        float rs = rsqrtf(var + 1e-5f);
        float acc = b2[0];
        #pragma unroll
        for (int m = 0; m < 5; ++m) {
            float zn = fmaf((z[m] - mu) * rs, lng[m], lnb[m]);
            acc = fmaf(zn, W2[m], acc);
        }
        out[b] = 1.f / (1.f + __expf(-acc));
    }
}

extern "C" void kernel_launch(void* const* d_in, const int* in_sizes, int n_in,
                              void* d_out, int out_size, void* d_ws, size_t ws_size,
                              hipStream_t stream) {
    const int*   tok   = (const int*)  d_in[0];
    const float* h0    = (const float*)d_in[1];
    const float* c0    = (const float*)d_in[2];
    const float* embed = (const float*)d_in[3];
    const float* Wih   = (const float*)d_in[4];
    const float* Whh   = (const float*)d_in[5];
    const float* bih   = (const float*)d_in[6];
    const float* bhh   = (const float*)d_in[7];
    const float* W1    = (const float*)d_in[8];
    const float* b1    = (const float*)d_in[9];
    const float* lng   = (const float*)d_in[10];
    const float* lnb   = (const float*)d_in[11];
    const float* W2    = (const float*)d_in[12];
    const float* b2    = (const float*)d_in[13];
    float* out  = (float*)d_out;
    float* proj = (float*)d_ws;   // VOCAB*GATES*4 = 5.12 MB

    hipLaunchKernelGGL(proj_kernel, dim3(2048), dim3(64), 0, stream,
                       embed, Wih, bih, bhh, proj);
    hipLaunchKernelGGL(lstm_rec, dim3(BSZ), dim3(64), 0, stream,
                       tok, proj, h0, c0, Whh, W1, b1, lng, lnb, W2, b2, out);
}

// Round 5
// 159.175 us; speedup vs baseline: 1.4795x; 1.4795x over previous
//
#include <hip/hip_runtime.h>
#include <math.h>

#define VOCAB 32000
#define EMBED 200
#define HID   10
#define GATES 40
#define BSZ   256
#define SEQ   512
#define PF    8     // prefetch depth (steps ahead) for proj gathers

__device__ __forceinline__ float rcp_fast(float x) { return __builtin_amdgcn_rcpf(x); }
__device__ __forceinline__ float sigmoid_fast(float x) {
    return rcp_fast(1.0f + __expf(-x));
}

// ---------------------------------------------------------------------------
// Kernel A: proj[v][g] = dot(embed_W[v,:], W_ih[g,:]) + b_ih[g] + b_hh[g]
// One wave per vocab row per grid-stride iter; lane g owns gate g and keeps
// its whole W_ih row in 50 float4 registers (one-time gather). Embed row
// loads are wave-uniform (scalarizable) and stream HBM once.
// ---------------------------------------------------------------------------
__global__ __launch_bounds__(64, 1) void proj_kernel(
    const float* __restrict__ embed, const float* __restrict__ Wih,
    const float* __restrict__ bih,   const float* __restrict__ bhh,
    float* __restrict__ proj)
{
    const int lane = threadIdx.x;
    const int gl   = lane < GATES ? lane : GATES - 1;   // clamp idle lanes
    const float bias = bih[gl] + bhh[gl];

    // register-cache this lane's W_ih row (200 floats)
    float4 w[EMBED / 4];
    const float4* wr = (const float4*)(Wih + gl * EMBED);
    #pragma unroll
    for (int k = 0; k < EMBED / 4; ++k) w[k] = wr[k];

    for (int v = blockIdx.x; v < VOCAB; v += gridDim.x) {
        const float4* er = (const float4*)(embed + (size_t)v * EMBED);
        float a0 = 0.f, a1 = 0.f, a2 = 0.f, a3 = 0.f;
        #pragma unroll
        for (int k = 0; k < EMBED / 4; k += 2) {
            float4 e0 = er[k];     float4 w0 = w[k];
            float4 e1 = er[k + 1]; float4 w1 = w[k + 1];
            a0 = fmaf(e0.x, w0.x, a0); a1 = fmaf(e0.y, w0.y, a1);
            a2 = fmaf(e0.z, w0.z, a2); a3 = fmaf(e0.w, w0.w, a3);
            a0 = fmaf(e1.x, w1.x, a0); a1 = fmaf(e1.y, w1.y, a1);
            a2 = fmaf(e1.z, w1.z, a2); a3 = fmaf(e1.w, w1.w, a3);
        }
        if (lane < GATES)
            proj[v * GATES + lane] = (a0 + a1) + (a2 + a3) + bias;
    }
}

// ---------------------------------------------------------------------------
// Kernel B: the recurrence. One wave per batch element. Lane g in [0,40)
// owns gate g (i:0-9, f:10-19, g:20-29, o:30-39). h replicated per lane;
// c owned by lanes 0..9. proj gathers prefetched PF=8 steps ahead (tokens
// 2*PF ahead) so L2/HBM latency is off the serial chain. h re-broadcast via
// 10 __shfl (lane-constant -> readlane); NO LDS cross-lane traffic (the
// wave-synchronous LDS broadcast in R2 was the correctness bug).
// ---------------------------------------------------------------------------
__global__ __launch_bounds__(64) void lstm_rec(
    const int*   __restrict__ tok,  const float* __restrict__ proj,
    const float* __restrict__ h0,   const float* __restrict__ c0,
    const float* __restrict__ Whh,
    const float* __restrict__ W1,   const float* __restrict__ b1,
    const float* __restrict__ lng,  const float* __restrict__ lnb,
    const float* __restrict__ W2,   const float* __restrict__ b2,
    float* __restrict__ out)
{
    __shared__ int tok_s[SEQ];

    const int b    = blockIdx.x;
    const int lane = threadIdx.x;
    const int gl   = lane < GATES ? lane : GATES - 1;

    #pragma unroll
    for (int k = 0; k < SEQ / 64; ++k)
        tok_s[k * 64 + lane] = tok[b * SEQ + k * 64 + lane];
    __syncthreads();

    // W_hh row for this gate
    float w[HID];
    #pragma unroll
    for (int j = 0; j < HID; ++j) w[j] = Whh[gl * HID + j];

    // replicated h, owned c
    float h_rep[HID];
    #pragma unroll
    for (int j = 0; j < HID; ++j) h_rep[j] = h0[b * HID + j];
    float c_own = (lane < HID) ? c0[b * HID + lane] : 0.f;

    // tanh-vs-sigmoid multiplier: gate lanes 20..29 compute tanh
    const float am  = (lane >= 20 && lane < 30) ? 2.f : 1.f;
    const float amc = 1.f - am;
    const int   j0  = lane % HID;
    const int   li  = j0, lf = j0 + 10, lg = j0 + 20, lo = j0 + 30;

    // ---- prefetch pipeline init ----
    float gx_ring[PF];   // proj value (this lane's gate) for steps s0..s0+PF-1
    int   t2_ring[PF];   // token for step s+PF (address source for prefetch)
    #pragma unroll
    for (int k = 0; k < PF; ++k) {
        gx_ring[k] = proj[tok_s[k] * GATES + gl];
        t2_ring[k] = tok_s[k + PF];
    }

    for (int s0 = 0; s0 < SEQ; s0 += PF) {
        #pragma unroll
        for (int k = 0; k < PF; ++k) {
            float gx = gx_ring[k];
            // issue prefetch for step s0+k+PF (uses token read PF steps ago)
            gx_ring[k] = proj[t2_ring[k] * GATES + gl];
            // read token for step s0+k+2*PF (consumed PF steps from now)
            int idx = s0 + k + 2 * PF;
            t2_ring[k] = tok_s[idx < SEQ ? idx : 0];

            // gates = gx + h . Whh_row  (two independent FMA chains)
            float a0 = gx, a1 = 0.f;
            a0 = fmaf(h_rep[0], w[0], a0); a1 = fmaf(h_rep[1], w[1], a1);
            a0 = fmaf(h_rep[2], w[2], a0); a1 = fmaf(h_rep[3], w[3], a1);
            a0 = fmaf(h_rep[4], w[4], a0); a1 = fmaf(h_rep[5], w[5], a1);
            a0 = fmaf(h_rep[6], w[6], a0); a1 = fmaf(h_rep[7], w[7], a1);
            a0 = fmaf(h_rep[8], w[8], a0); a1 = fmaf(h_rep[9], w[9], a1);
            float acc = a0 + a1;

            // branchless sigmoid/tanh: val = am*sigmoid(am*acc) + (1-am)
            float sg  = sigmoid_fast(am * acc);
            float val = fmaf(am, sg, amc);

            // gather i,f,g,o for hidden unit j0
            float iv = __shfl(val, li, 64);
            float fv = __shfl(val, lf, 64);
            float gv = __shfl(val, lg, 64);
            float ov = __shfl(val, lo, 64);

            c_own = fmaf(fv, c_own, iv * gv);                         // c = f*c + i*g
            float th    = fmaf(2.f, sigmoid_fast(2.f * c_own), -1.f); // tanh(c)
            float h_own = ov * th;

            // re-broadcast h to all lanes (lane-constant shfl -> readlane)
            #pragma unroll
            for (int j = 0; j < HID; ++j) h_rep[j] = __shfl(h_own, j, 64);
        }
    }

    // head: z = hn@W1^T + b1 ; LayerNorm(5) ; sigmoid(z@W2^T + b2)
    if (lane == 0) {
        float z[5];
        float mu = 0.f;
        #pragma unroll
        for (int m = 0; m < 5; ++m) {
            float a = b1[m];
            #pragma unroll
            for (int j = 0; j < HID; ++j) a = fmaf(h_rep[j], W1[m * HID + j], a);
            z[m] = a; mu += a;
        }
        mu *= 0.2f;
        float var = 0.f;
        #pragma unroll
        for (int m = 0; m < 5; ++m) { float d = z[m] - mu; var = fmaf(d, d, var); }
        var *= 0.2f;
        float rs = rsqrtf(var + 1e-5f);
        float acc = b2[0];
        #pragma unroll
        for (int m = 0; m < 5; ++m) {
            float zn = fmaf((z[m] - mu) * rs, lng[m], lnb[m]);
            acc = fmaf(zn, W2[m], acc);
        }
        out[b] = 1.f / (1.f + __expf(-acc));
    }
}

extern "C" void kernel_launch(void* const* d_in, const int* in_sizes, int n_in,
                              void* d_out, int out_size, void* d_ws, size_t ws_size,
                              hipStream_t stream) {
    const int*   tok   = (const int*)  d_in[0];
    const float* h0    = (const float*)d_in[1];
    const float* c0    = (const float*)d_in[2];
    const float* embed = (const float*)d_in[3];
    const float* Wih   = (const float*)d_in[4];
    const float* Whh   = (const float*)d_in[5];
    const float* bih   = (const float*)d_in[6];
    const float* bhh   = (const float*)d_in[7];
    const float* W1    = (const float*)d_in[8];
    const float* b1    = (const float*)d_in[9];
    const float* lng   = (const float*)d_in[10];
    const float* lnb   = (const float*)d_in[11];
    const float* W2    = (const float*)d_in[12];
    const float* b2    = (const float*)d_in[13];
    float* out  = (float*)d_out;
    float* proj = (float*)d_ws;   // VOCAB*GATES*4 = 5.12 MB

    hipLaunchKernelGGL(proj_kernel, dim3(2048), dim3(64), 0, stream,
                       embed, Wih, bih, bhh, proj);
    hipLaunchKernelGGL(lstm_rec, dim3(BSZ), dim3(64), 0, stream,
                       tok, proj, h0, c0, Whh, W1, b1, lng, lnb, W2, b2, out);
}